// Round 15
// baseline (156.844 us; speedup 1.0000x reference)
//
#include <hip/hip_runtime.h>
#include <hip/hip_bf16.h>

// B=256, C_IN=6, L=512, C1=32, C2=D=64, NCLASS=10.
// Megakernel v6 (consolidation of best-measured pieces):
//  - prep_all v2: LDS-staged coalesced im2col (R14; ~5us)
//  - fused_all: R13's attention loop (single K-prefetch, V in-loop) + exp2
//    fold (R14). conv1/conv2/qkv all MFMA, BN folded, distributed K/V slabs.
// LDS 151.6 KB. ws: prepped weights + ximg.

#define NB 256
#define LL 512
#define CIN 6
#define NCLASS 10
#define SLAB 9472
#define QSC 0.18033688f   // 0.125 * log2(e): exp(s/8) == exp2(s*QSC)

typedef __bf16 bf16x8 __attribute__((ext_vector_type(8)));
typedef float f32x4 __attribute__((ext_vector_type(4)));
typedef unsigned short us4 __attribute__((ext_vector_type(4)));

static __device__ __forceinline__ unsigned short f2b(float f) {
    __bf16 h = (__bf16)f;                       // RNE f32->bf16
    return __builtin_bit_cast(unsigned short, h);
}

// ---------------------------------------------------------------------------
// Kernel P v2: per-batch im2col via LDS staging (coalesced both directions).
// ximg[b][wave][48][32] bf16. Block 0 also folds BN into bf16 weights.
// ---------------------------------------------------------------------------
__global__ __launch_bounds__(256) void prep_all(
    const float* __restrict__ x,
    const float* __restrict__ w1, const float* __restrict__ cb1,
    const float* __restrict__ g1, const float* __restrict__ be1,
    const float* __restrict__ m1, const float* __restrict__ v1,
    const float* __restrict__ w2, const float* __restrict__ cb2,
    const float* __restrict__ g2, const float* __restrict__ be2,
    const float* __restrict__ m2, const float* __restrict__ v2,
    const float* __restrict__ wq, const float* __restrict__ wk,
    const float* __restrict__ wv,
    unsigned short* __restrict__ ximg,
    unsigned short* __restrict__ w1p, float* __restrict__ b1f,
    unsigned short* __restrict__ w2p, float* __restrict__ b2f,
    unsigned short* __restrict__ wqp, unsigned short* __restrict__ wkp,
    unsigned short* __restrict__ wvp)
{
    const int b = blockIdx.x;
    const int t = threadIdx.x;

    __shared__ float xs[CIN][LL];
    for (int i = t; i < 768; i += 256) {         // 6*512 f32 = 768 float4
        int ci = i / 128, j4 = i % 128;
        *(float4*)&xs[ci][j4 * 4] = *(const float4*)(x + ((size_t)b * CIN + ci) * LL + j4 * 4);
    }
    __syncthreads();

    for (int idx = t; idx < 16 * 48 * 8; idx += 256) {   // us4 units
        int wv = idx / 384;
        int rem = idx - wv * 384;
        int j = rem >> 3, kg = rem & 7;
        us4 pk = {0, 0, 0, 0};
        if (j < 34) {
            #pragma unroll
            for (int u = 0; u < 4; u++) {
                int k = kg * 4 + u;
                if (k < 18) {
                    int ci = k / 3, dl = k - ci * 3;
                    int l = wv * 32 - 2 + j + dl;
                    float v = (l >= 0 && l < LL) ? xs[ci][l] : 0.f;
                    pk[u] = f2b(v);
                }
            }
        }
        *(us4*)&ximg[((size_t)(b * 16 + wv) * 48 + j) * 32 + kg * 4] = pk;
    }

    if (b != 0) return;
    // ---- weights (block 0 only) ------------------------------------------
    for (int idx = t; idx < 1024; idx += 256) {       // w1p [32][32]
        int c = idx >> 5, k = idx & 31;
        float inv = g1[c] * rsqrtf(v1[c] + 1e-5f);
        float val = (k < 18) ? w1[c * 18 + k] * inv : 0.f;
        w1p[idx] = f2b(val);
    }
    if (t < 32) {
        float inv = g1[t] * rsqrtf(v1[t] + 1e-5f);
        b1f[t] = be1[t] + (cb1[t] - m1[t]) * inv;
    }
    for (int idx = t; idx < 2048; idx += 256) {       // w2p [64][96], k'=dl*32+ci
        int c2 = idx >> 5, ci = idx & 31;
        float inv = g2[c2] * rsqrtf(v2[c2] + 1e-5f);
        const float* wp = w2 + c2 * 96 + ci * 3;
        w2p[c2 * 96 +      ci] = f2b(wp[0] * inv);
        w2p[c2 * 96 + 32 + ci] = f2b(wp[1] * inv);
        w2p[c2 * 96 + 64 + ci] = f2b(wp[2] * inv);
    }
    if (t >= 64 && t < 128) {
        int c2 = t - 64;
        float inv = g2[c2] * rsqrtf(v2[c2] + 1e-5f);
        b2f[c2] = be2[c2] + (cb2[c2] - m2[c2]) * inv;
    }
    for (int idx = t; idx < 4096; idx += 256) {
        wqp[idx] = f2b(wq[idx] * QSC);                // fold 1/8 * log2e
        wkp[idx] = f2b(wk[idx]);
        wvp[idx] = f2b(wv[idx]);
    }
}

// ---------------------------------------------------------------------------
// Megakernel v6. Slab (9472 B/wave), aliased phases (same-wave in-order DS):
//   conv: h1sl[34][40] @3072 (2720) | Ts[32][72] @4608
//   attn: Kf @0 (4096) | Vf @4096 (4096) | Ps[16][40] @8192 (1280)
//   epi : redw f32[64] @8192 (aliases Ps) ; pooled @ smem+8448 (slab0)
// ---------------------------------------------------------------------------
__global__ __launch_bounds__(1024, 4) void fused_all(
    const unsigned short* __restrict__ ximg,
    const unsigned short* __restrict__ w1p, const float* __restrict__ b1f,
    const unsigned short* __restrict__ w2p, const float* __restrict__ b2f,
    const unsigned short* __restrict__ wqp, const unsigned short* __restrict__ wkp,
    const unsigned short* __restrict__ wvp,
    const float* __restrict__ bq, const float* __restrict__ bk,
    const float* __restrict__ bvp,
    const float* __restrict__ fcw, const float* __restrict__ fcb,
    float* __restrict__ outp)
{
    const int b = blockIdx.x;
    const int t = threadIdx.x;
    const int w = t >> 6, lane = t & 63, quad = lane >> 4, lc = lane & 15;

    __shared__ __align__(16) char smem[16 * SLAB];   // 151552 B
    char* myslab = smem + w * SLAB;
    unsigned short* h1sl = (unsigned short*)(myslab + 3072);
    unsigned short* Ts   = (unsigned short*)(myslab + 4608);
    unsigned short* Kf   = (unsigned short*)myslab;
    unsigned short* Vf   = (unsigned short*)(myslab + 4096);
    unsigned short* Ps   = (unsigned short*)(myslab + 8192);
    float* redw   = (float*)(myslab + 8192);         // epilogue alias of Ps
    float* pooled = (float*)(smem + 8448);           // slab0, after wave0 redw

    // ---- P1: conv1 as MFMA, A-frags DIRECT from global ximg --------------
    const unsigned short* xw = ximg + (size_t)(b * 16 + w) * 1536;
    bf16x8 bW1[2];
    #pragma unroll
    for (int nt = 0; nt < 2; nt++)
        bW1[nt] = *(const bf16x8*)(w1p + (nt * 16 + lc) * 32 + quad * 8);
    float b1v[2] = {b1f[lc], b1f[16 + lc]};
    f32x4 h1acc[3][2];
    #pragma unroll
    for (int mt = 0; mt < 3; mt++) {
        bf16x8 aX = *(const bf16x8*)(xw + (mt * 16 + lc) * 32 + quad * 8);
        #pragma unroll
        for (int nt = 0; nt < 2; nt++) {
            f32x4 z = {0.f, 0.f, 0.f, 0.f};
            h1acc[mt][nt] = __builtin_amdgcn_mfma_f32_16x16x32_bf16(aX, bW1[nt], z, 0, 0, 0);
        }
    }
    #pragma unroll
    for (int mt = 0; mt < 3; mt++)
        #pragma unroll
        for (int nt = 0; nt < 2; nt++)
            #pragma unroll
            for (int r = 0; r < 4; r++) {
                int j = mt * 16 + quad * 4 + r;
                if (j < 34) {
                    int pos = w * 32 - 1 + j;
                    float y = h1acc[mt][nt][r] + b1v[nt];
                    y = (pos >= 0 && pos < LL && y > 0.f) ? y : 0.f;
                    h1sl[j * 40 + nt * 16 + lc] = f2b(y);
                }
            }

    // ---- P2: conv2 as GEMM (M=64 c2, N=32 rows, K=96; k'=dl*32+ci) -------
    bf16x8 bX[2][3], aW2[4][3];
    #pragma unroll
    for (int rt = 0; rt < 2; rt++)
        #pragma unroll
        for (int kc = 0; kc < 3; kc++)
            bX[rt][kc] = *(const bf16x8*)&h1sl[(rt * 16 + lc + kc) * 40 + quad * 8];
    #pragma unroll
    for (int nt = 0; nt < 4; nt++)
        #pragma unroll
        for (int kc = 0; kc < 3; kc++)
            aW2[nt][kc] = *(const bf16x8*)(w2p + (nt * 16 + lc) * 96 + kc * 32 + quad * 8);

    f32x4 acc2[4][2];
    #pragma unroll
    for (int nt = 0; nt < 4; nt++)
        #pragma unroll
        for (int rt = 0; rt < 2; rt++) {
            f32x4 a = {0.f, 0.f, 0.f, 0.f};
            a = __builtin_amdgcn_mfma_f32_16x16x32_bf16(aW2[nt][0], bX[rt][0], a, 0, 0, 0);
            a = __builtin_amdgcn_mfma_f32_16x16x32_bf16(aW2[nt][1], bX[rt][1], a, 0, 0, 0);
            acc2[nt][rt] = __builtin_amdgcn_mfma_f32_16x16x32_bf16(aW2[nt][2], bX[rt][2], a, 0, 0, 0);
        }

    // ---- P3a: +b2f, relu -> Ts[row][c2] ----------------------------------
    #pragma unroll
    for (int nt = 0; nt < 4; nt++) {
        const float4 bb2 = *(const float4*)&b2f[nt * 16 + quad * 4];
        #pragma unroll
        for (int rt = 0; rt < 2; rt++) {
            us4 pk;
            float y0 = acc2[nt][rt][0] + bb2.x; pk[0] = f2b(y0 > 0.f ? y0 : 0.f);
            float y1 = acc2[nt][rt][1] + bb2.y; pk[1] = f2b(y1 > 0.f ? y1 : 0.f);
            float y2 = acc2[nt][rt][2] + bb2.z; pk[2] = f2b(y2 > 0.f ? y2 : 0.f);
            float y3 = acc2[nt][rt][3] + bb2.w; pk[3] = f2b(y3 > 0.f ? y3 : 0.f);
            *(us4*)&Ts[(rt * 16 + lc) * 72 + nt * 16 + quad * 4] = pk;
        }
    }
    bf16x8 aH[2][2];
    #pragma unroll
    for (int rt = 0; rt < 2; rt++)
        #pragma unroll
        for (int kc = 0; kc < 2; kc++)
            aH[rt][kc] = *(const bf16x8*)&Ts[(rt * 16 + lc) * 72 + kc * 32 + quad * 8];

    // ---- P3b: q (regs, exp2-scaled) then k (straight into slab Kf) -------
    bf16x8 aQ[2][2];
    for (int p = 0; p < 2; p++) {
        const unsigned short* wsrc = p ? wkp : wqp;
        const float* bsrc = p ? bk : bq;
        const float bscl = p ? 1.0f : QSC;
        #pragma unroll
        for (int nt = 0; nt < 4; nt++) {
            bf16x8 aW[2];
            #pragma unroll
            for (int kc = 0; kc < 2; kc++)
                aW[kc] = *(const bf16x8*)(wsrc + (nt * 16 + lc) * 64 + kc * 32 + quad * 8);
            float4 bb = *(const float4*)&bsrc[nt * 16 + quad * 4];
            bb.x *= bscl; bb.y *= bscl; bb.z *= bscl; bb.w *= bscl;
            #pragma unroll
            for (int rt = 0; rt < 2; rt++) {
                f32x4 a = {0.f, 0.f, 0.f, 0.f};
                a = __builtin_amdgcn_mfma_f32_16x16x32_bf16(aW[0], aH[rt][0], a, 0, 0, 0);
                a = __builtin_amdgcn_mfma_f32_16x16x32_bf16(aW[1], aH[rt][1], a, 0, 0, 0);
                us4 pk;
                pk[0] = f2b(a[0] + bb.x); pk[1] = f2b(a[1] + bb.y);
                pk[2] = f2b(a[2] + bb.z); pk[3] = f2b(a[3] + bb.w);
                *(us4*)&Ts[(rt * 16 + lc) * 72 + nt * 16 + quad * 4] = pk;
            }
        }
        #pragma unroll
        for (int rt = 0; rt < 2; rt++)
            #pragma unroll
            for (int kc = 0; kc < 2; kc++) {
                bf16x8 fr = *(const bf16x8*)&Ts[(rt * 16 + lc) * 72 + kc * 32 + quad * 8];
                if (p == 0) aQ[rt][kc] = fr;
                else *(bf16x8*)&Kf[((rt * 2 + kc) << 9) + lane * 8] = fr;
            }
    }

    // ---- P3c: v -> Vf, B-frag lane-linear (frag stride 512 shorts) -------
    #pragma unroll
    for (int nt = 0; nt < 4; nt++) {
        bf16x8 bW[2];
        #pragma unroll
        for (int kc = 0; kc < 2; kc++)
            bW[kc] = *(const bf16x8*)(wvp + (nt * 16 + lc) * 64 + kc * 32 + quad * 8);
        const float bvv = bvp[nt * 16 + lc];
        #pragma unroll
        for (int rt = 0; rt < 2; rt++) {
            f32x4 a = {0.f, 0.f, 0.f, 0.f};
            a = __builtin_amdgcn_mfma_f32_16x16x32_bf16(aH[rt][0], bW[0], a, 0, 0, 0);
            a = __builtin_amdgcn_mfma_f32_16x16x32_bf16(aH[rt][1], bW[1], a, 0, 0, 0);
            us4 pk;
            pk[0] = f2b(a[0] + bvv); pk[1] = f2b(a[1] + bvv);
            pk[2] = f2b(a[2] + bvv); pk[3] = f2b(a[3] + bvv);
            *(us4*)&Vf[nt * 512 + ((rt * 2 + (quad >> 1)) * 16 + lc) * 8 + (quad & 1) * 4] = pk;
        }
    }

    __syncthreads();          // all waves' Kf/Vf ready — only pre-attn barrier

    // ---- attention: single pass, 16 chunks, K-frag register prefetch -----
    f32x4 outacc[2][4];
    #pragma unroll
    for (int rt = 0; rt < 2; rt++)
        #pragma unroll
        for (int dt = 0; dt < 4; dt++) outacc[rt][dt] = (f32x4){0.f, 0.f, 0.f, 0.f};
    float den[2][4] = {{0.f, 0.f, 0.f, 0.f}, {0.f, 0.f, 0.f, 0.f}};

    bf16x8 bK[2][2], bKn[2][2];
    {
        const unsigned short* sK = (const unsigned short*)smem;   // chunk 0
        #pragma unroll
        for (int nt = 0; nt < 2; nt++)
            #pragma unroll
            for (int kc = 0; kc < 2; kc++)
                bK[nt][kc] = *(const bf16x8*)&sK[((nt * 2 + kc) << 9) + lane * 8];
    }

    for (int cc = 0; cc < 16; cc++) {
        f32x4 sv[2][2];
        #pragma unroll
        for (int rt = 0; rt < 2; rt++)
            #pragma unroll
            for (int nt = 0; nt < 2; nt++) {
                f32x4 z = {0.f, 0.f, 0.f, 0.f};
                z = __builtin_amdgcn_mfma_f32_16x16x32_bf16(aQ[rt][0], bK[nt][0], z, 0, 0, 0);
                sv[rt][nt] = __builtin_amdgcn_mfma_f32_16x16x32_bf16(aQ[rt][1], bK[nt][1], z, 0, 0, 0);
            }
        const unsigned short* sV = (const unsigned short*)(smem + cc * SLAB + 4096);
        bf16x8 bV[4];
        #pragma unroll
        for (int dt = 0; dt < 4; dt++)
            bV[dt] = *(const bf16x8*)&sV[dt * 512 + lane * 8];
        #pragma unroll
        for (int nt = 0; nt < 2; nt++)
            #pragma unroll
            for (int reg = 0; reg < 4; reg++) {
                float pr = exp2f(sv[0][nt][reg]);     // q pre-scaled by log2e/8
                den[0][reg] += pr;
                Ps[(quad * 4 + reg) * 40 + nt * 16 + lc] = f2b(pr);
            }
        if (cc < 15) {                                // prefetch next K frags
            const unsigned short* sKn = (const unsigned short*)(smem + (cc + 1) * SLAB);
            #pragma unroll
            for (int nt = 0; nt < 2; nt++)
                #pragma unroll
                for (int kc = 0; kc < 2; kc++)
                    bKn[nt][kc] = *(const bf16x8*)&sKn[((nt * 2 + kc) << 9) + lane * 8];
        }
        bf16x8 aP0 = *(const bf16x8*)&Ps[lc * 40 + quad * 8];
        #pragma unroll
        for (int nt = 0; nt < 2; nt++)
            #pragma unroll
            for (int reg = 0; reg < 4; reg++) {
                float pr = exp2f(sv[1][nt][reg]);
                den[1][reg] += pr;
                Ps[(quad * 4 + reg) * 40 + nt * 16 + lc] = f2b(pr);
            }
        #pragma unroll
        for (int dt = 0; dt < 4; dt++)
            outacc[0][dt] = __builtin_amdgcn_mfma_f32_16x16x32_bf16(aP0, bV[dt], outacc[0][dt], 0, 0, 0);
        bf16x8 aP1 = *(const bf16x8*)&Ps[lc * 40 + quad * 8];
        #pragma unroll
        for (int dt = 0; dt < 4; dt++)
            outacc[1][dt] = __builtin_amdgcn_mfma_f32_16x16x32_bf16(aP1, bV[dt], outacc[1][dt], 0, 0, 0);
        #pragma unroll
        for (int nt = 0; nt < 2; nt++)
            #pragma unroll
            for (int kc = 0; kc < 2; kc++)
                bK[nt][kc] = bKn[nt][kc];
    }

    // ---- epilogue: den reduce (quad 16-lane classes), pooled, fc ---------
    float rden[2][4];
    #pragma unroll
    for (int rt = 0; rt < 2; rt++)
        #pragma unroll
        for (int reg = 0; reg < 4; reg++) {
            float d2 = den[rt][reg];
            d2 += __shfl_xor(d2, 1);  d2 += __shfl_xor(d2, 2);
            d2 += __shfl_xor(d2, 4);  d2 += __shfl_xor(d2, 8);
            rden[rt][reg] = 1.0f / d2;
        }
    #pragma unroll
    for (int dt = 0; dt < 4; dt++) {
        float ps = 0.f;
        #pragma unroll
        for (int rt = 0; rt < 2; rt++)
            #pragma unroll
            for (int reg = 0; reg < 4; reg++)
                ps += outacc[rt][dt][reg] * rden[rt][reg];
        ps += __shfl_xor(ps, 16);
        ps += __shfl_xor(ps, 32);
        if (quad == 0) redw[dt * 16 + lc] = ps;     // aliases dead Ps
    }
    __syncthreads();
    if (t < 64) {
        float s = 0.f;
        #pragma unroll
        for (int ww = 0; ww < 16; ww++)
            s += *(const float*)(smem + ww * SLAB + 8192 + t * 4);
        pooled[t] = s * (1.0f / 512.0f);
    }
    __syncthreads();
    if (t < NCLASS) {
        float acc = fcb[t];
        #pragma unroll
        for (int d = 0; d < 64; d++) acc += pooled[d] * fcw[t * 64 + d];
        outp[b * NCLASS + t] = acc;
    }
}

// ---------------------------------------------------------------------------
extern "C" void kernel_launch(void* const* d_in, const int* in_sizes, int n_in,
                              void* d_out, int out_size, void* d_ws, size_t ws_size,
                              hipStream_t stream)
{
    const float* x   = (const float*)d_in[0];
    const float* w1  = (const float*)d_in[1];
    const float* cb1 = (const float*)d_in[2];
    const float* g1  = (const float*)d_in[3];
    const float* be1 = (const float*)d_in[4];
    const float* m1  = (const float*)d_in[5];
    const float* v1  = (const float*)d_in[6];
    const float* w2  = (const float*)d_in[7];
    const float* cb2 = (const float*)d_in[8];
    const float* g2  = (const float*)d_in[9];
    const float* be2 = (const float*)d_in[10];
    const float* m2  = (const float*)d_in[11];
    const float* v2  = (const float*)d_in[12];
    const float* wq  = (const float*)d_in[13];
    const float* bq  = (const float*)d_in[14];
    const float* wk  = (const float*)d_in[15];
    const float* bk  = (const float*)d_in[16];
    const float* wv  = (const float*)d_in[17];
    const float* bv  = (const float*)d_in[18];
    const float* fcw = (const float*)d_in[19];
    const float* fcb = (const float*)d_in[20];
    float* out = (float*)d_out;

    char* ws = (char*)d_ws;
    unsigned short* w1p = (unsigned short*)(ws);            // 2048 B
    float*          b1f = (float*)(ws + 2048u);             // 128 B
    float*          b2f = (float*)(ws + 2176u);             // 256 B
    unsigned short* w2p = (unsigned short*)(ws + 2432u);    // 12288 B
    unsigned short* wqp = (unsigned short*)(ws + 14720u);   // 8192 B
    unsigned short* wkp = (unsigned short*)(ws + 22912u);   // 8192 B
    unsigned short* wvp = (unsigned short*)(ws + 31104u);   // 8192 B
    unsigned short* ximg = (unsigned short*)(ws + 40960u);  // 12,582,912 B

    prep_all<<<dim3(NB), 256, 0, stream>>>(x,
                                           w1, cb1, g1, be1, m1, v1,
                                           w2, cb2, g2, be2, m2, v2,
                                           wq, wk, wv,
                                           ximg, w1p, b1f, w2p, b2f, wqp, wkp, wvp);
    fused_all<<<dim3(NB), 1024, 0, stream>>>(ximg, w1p, b1f, w2p, b2f,
                                             wqp, wkp, wvp,
                                             bq, bk, bv, fcw, fcb, out);
}

// Round 16
// 150.118 us; speedup vs baseline: 1.0448x; 1.0448x over previous
//
#include <hip/hip_runtime.h>
#include <hip/hip_bf16.h>

// B=256, C_IN=6, L=512, C1=32, C2=D=64, NCLASS=10.
// Megakernel v7: R13's best-measured fused structure + fast prep (R14) +
// softmax exp as a SINGLE v_exp_f32 via __builtin_amdgcn_exp2f (QSC folded
// into wqp/bq). R15 post-mortem: libm exp2f() is the precise path (range
// fixup code) and cost +4.7us vs __expf; the raw builtin is 1 instruction.
// LDS 151.6 KB. ws: prepped weights + ximg.

#define NB 256
#define LL 512
#define CIN 6
#define NCLASS 10
#define SLAB 9472
#define QSC 0.18033688f   // 0.125 * log2(e): exp(s/8) == exp2(s*QSC)

typedef __bf16 bf16x8 __attribute__((ext_vector_type(8)));
typedef float f32x4 __attribute__((ext_vector_type(4)));
typedef unsigned short us4 __attribute__((ext_vector_type(4)));

static __device__ __forceinline__ unsigned short f2b(float f) {
    __bf16 h = (__bf16)f;                       // RNE f32->bf16
    return __builtin_bit_cast(unsigned short, h);
}

// ---------------------------------------------------------------------------
// Kernel P v2: per-batch im2col via LDS staging (coalesced both directions).
// ximg[b][wave][48][32] bf16. Block 0 also folds BN into bf16 weights.
// ---------------------------------------------------------------------------
__global__ __launch_bounds__(256) void prep_all(
    const float* __restrict__ x,
    const float* __restrict__ w1, const float* __restrict__ cb1,
    const float* __restrict__ g1, const float* __restrict__ be1,
    const float* __restrict__ m1, const float* __restrict__ v1,
    const float* __restrict__ w2, const float* __restrict__ cb2,
    const float* __restrict__ g2, const float* __restrict__ be2,
    const float* __restrict__ m2, const float* __restrict__ v2,
    const float* __restrict__ wq, const float* __restrict__ wk,
    const float* __restrict__ wv,
    unsigned short* __restrict__ ximg,
    unsigned short* __restrict__ w1p, float* __restrict__ b1f,
    unsigned short* __restrict__ w2p, float* __restrict__ b2f,
    unsigned short* __restrict__ wqp, unsigned short* __restrict__ wkp,
    unsigned short* __restrict__ wvp)
{
    const int b = blockIdx.x;
    const int t = threadIdx.x;

    __shared__ float xs[CIN][LL];
    for (int i = t; i < 768; i += 256) {         // 6*512 f32 = 768 float4
        int ci = i / 128, j4 = i % 128;
        *(float4*)&xs[ci][j4 * 4] = *(const float4*)(x + ((size_t)b * CIN + ci) * LL + j4 * 4);
    }
    __syncthreads();

    for (int idx = t; idx < 16 * 48 * 8; idx += 256) {   // us4 units
        int wv = idx / 384;
        int rem = idx - wv * 384;
        int j = rem >> 3, kg = rem & 7;
        us4 pk = {0, 0, 0, 0};
        if (j < 34) {
            #pragma unroll
            for (int u = 0; u < 4; u++) {
                int k = kg * 4 + u;
                if (k < 18) {
                    int ci = k / 3, dl = k - ci * 3;
                    int l = wv * 32 - 2 + j + dl;
                    float v = (l >= 0 && l < LL) ? xs[ci][l] : 0.f;
                    pk[u] = f2b(v);
                }
            }
        }
        *(us4*)&ximg[((size_t)(b * 16 + wv) * 48 + j) * 32 + kg * 4] = pk;
    }

    if (b != 0) return;
    // ---- weights (block 0 only) ------------------------------------------
    for (int idx = t; idx < 1024; idx += 256) {       // w1p [32][32]
        int c = idx >> 5, k = idx & 31;
        float inv = g1[c] * rsqrtf(v1[c] + 1e-5f);
        float val = (k < 18) ? w1[c * 18 + k] * inv : 0.f;
        w1p[idx] = f2b(val);
    }
    if (t < 32) {
        float inv = g1[t] * rsqrtf(v1[t] + 1e-5f);
        b1f[t] = be1[t] + (cb1[t] - m1[t]) * inv;
    }
    for (int idx = t; idx < 2048; idx += 256) {       // w2p [64][96], k'=dl*32+ci
        int c2 = idx >> 5, ci = idx & 31;
        float inv = g2[c2] * rsqrtf(v2[c2] + 1e-5f);
        const float* wp = w2 + c2 * 96 + ci * 3;
        w2p[c2 * 96 +      ci] = f2b(wp[0] * inv);
        w2p[c2 * 96 + 32 + ci] = f2b(wp[1] * inv);
        w2p[c2 * 96 + 64 + ci] = f2b(wp[2] * inv);
    }
    if (t >= 64 && t < 128) {
        int c2 = t - 64;
        float inv = g2[c2] * rsqrtf(v2[c2] + 1e-5f);
        b2f[c2] = be2[c2] + (cb2[c2] - m2[c2]) * inv;
    }
    for (int idx = t; idx < 4096; idx += 256) {
        wqp[idx] = f2b(wq[idx] * QSC);                // fold 1/8 * log2e
        wkp[idx] = f2b(wk[idx]);
        wvp[idx] = f2b(wv[idx]);
    }
}

// ---------------------------------------------------------------------------
// Megakernel v7. Slab (9472 B/wave), aliased phases (same-wave in-order DS):
//   conv: h1sl[34][40] @3072 (2720) | Ts[32][72] @4608
//   attn: Kf @0 (4096) | Vf @4096 (4096) | Ps[16][40] @8192 (1280)
//   epi : redw f32[64] @8192 (aliases Ps) ; pooled @ smem+8448 (slab0)
// ---------------------------------------------------------------------------
__global__ __launch_bounds__(1024, 4) void fused_all(
    const unsigned short* __restrict__ ximg,
    const unsigned short* __restrict__ w1p, const float* __restrict__ b1f,
    const unsigned short* __restrict__ w2p, const float* __restrict__ b2f,
    const unsigned short* __restrict__ wqp, const unsigned short* __restrict__ wkp,
    const unsigned short* __restrict__ wvp,
    const float* __restrict__ bq, const float* __restrict__ bk,
    const float* __restrict__ bvp,
    const float* __restrict__ fcw, const float* __restrict__ fcb,
    float* __restrict__ outp)
{
    const int b = blockIdx.x;
    const int t = threadIdx.x;
    const int w = t >> 6, lane = t & 63, quad = lane >> 4, lc = lane & 15;

    __shared__ __align__(16) char smem[16 * SLAB];   // 151552 B
    char* myslab = smem + w * SLAB;
    unsigned short* h1sl = (unsigned short*)(myslab + 3072);
    unsigned short* Ts   = (unsigned short*)(myslab + 4608);
    unsigned short* Kf   = (unsigned short*)myslab;
    unsigned short* Vf   = (unsigned short*)(myslab + 4096);
    unsigned short* Ps   = (unsigned short*)(myslab + 8192);
    float* redw   = (float*)(myslab + 8192);         // epilogue alias of Ps
    float* pooled = (float*)(smem + 8448);           // slab0, after wave0 redw

    // ---- P1: conv1 as MFMA, A-frags DIRECT from global ximg --------------
    const unsigned short* xw = ximg + (size_t)(b * 16 + w) * 1536;
    bf16x8 bW1[2];
    #pragma unroll
    for (int nt = 0; nt < 2; nt++)
        bW1[nt] = *(const bf16x8*)(w1p + (nt * 16 + lc) * 32 + quad * 8);
    float b1v[2] = {b1f[lc], b1f[16 + lc]};
    f32x4 h1acc[3][2];
    #pragma unroll
    for (int mt = 0; mt < 3; mt++) {
        bf16x8 aX = *(const bf16x8*)(xw + (mt * 16 + lc) * 32 + quad * 8);
        #pragma unroll
        for (int nt = 0; nt < 2; nt++) {
            f32x4 z = {0.f, 0.f, 0.f, 0.f};
            h1acc[mt][nt] = __builtin_amdgcn_mfma_f32_16x16x32_bf16(aX, bW1[nt], z, 0, 0, 0);
        }
    }
    #pragma unroll
    for (int mt = 0; mt < 3; mt++)
        #pragma unroll
        for (int nt = 0; nt < 2; nt++)
            #pragma unroll
            for (int r = 0; r < 4; r++) {
                int j = mt * 16 + quad * 4 + r;
                if (j < 34) {
                    int pos = w * 32 - 1 + j;
                    float y = h1acc[mt][nt][r] + b1v[nt];
                    y = (pos >= 0 && pos < LL && y > 0.f) ? y : 0.f;
                    h1sl[j * 40 + nt * 16 + lc] = f2b(y);
                }
            }

    // ---- P2: conv2 as GEMM (M=64 c2, N=32 rows, K=96; k'=dl*32+ci) -------
    bf16x8 bX[2][3], aW2[4][3];
    #pragma unroll
    for (int rt = 0; rt < 2; rt++)
        #pragma unroll
        for (int kc = 0; kc < 3; kc++)
            bX[rt][kc] = *(const bf16x8*)&h1sl[(rt * 16 + lc + kc) * 40 + quad * 8];
    #pragma unroll
    for (int nt = 0; nt < 4; nt++)
        #pragma unroll
        for (int kc = 0; kc < 3; kc++)
            aW2[nt][kc] = *(const bf16x8*)(w2p + (nt * 16 + lc) * 96 + kc * 32 + quad * 8);

    f32x4 acc2[4][2];
    #pragma unroll
    for (int nt = 0; nt < 4; nt++)
        #pragma unroll
        for (int rt = 0; rt < 2; rt++) {
            f32x4 a = {0.f, 0.f, 0.f, 0.f};
            a = __builtin_amdgcn_mfma_f32_16x16x32_bf16(aW2[nt][0], bX[rt][0], a, 0, 0, 0);
            a = __builtin_amdgcn_mfma_f32_16x16x32_bf16(aW2[nt][1], bX[rt][1], a, 0, 0, 0);
            acc2[nt][rt] = __builtin_amdgcn_mfma_f32_16x16x32_bf16(aW2[nt][2], bX[rt][2], a, 0, 0, 0);
        }

    // ---- P3a: +b2f, relu -> Ts[row][c2] ----------------------------------
    #pragma unroll
    for (int nt = 0; nt < 4; nt++) {
        const float4 bb2 = *(const float4*)&b2f[nt * 16 + quad * 4];
        #pragma unroll
        for (int rt = 0; rt < 2; rt++) {
            us4 pk;
            float y0 = acc2[nt][rt][0] + bb2.x; pk[0] = f2b(y0 > 0.f ? y0 : 0.f);
            float y1 = acc2[nt][rt][1] + bb2.y; pk[1] = f2b(y1 > 0.f ? y1 : 0.f);
            float y2 = acc2[nt][rt][2] + bb2.z; pk[2] = f2b(y2 > 0.f ? y2 : 0.f);
            float y3 = acc2[nt][rt][3] + bb2.w; pk[3] = f2b(y3 > 0.f ? y3 : 0.f);
            *(us4*)&Ts[(rt * 16 + lc) * 72 + nt * 16 + quad * 4] = pk;
        }
    }
    bf16x8 aH[2][2];
    #pragma unroll
    for (int rt = 0; rt < 2; rt++)
        #pragma unroll
        for (int kc = 0; kc < 2; kc++)
            aH[rt][kc] = *(const bf16x8*)&Ts[(rt * 16 + lc) * 72 + kc * 32 + quad * 8];

    // ---- P3b: q (regs, QSC-scaled) then k (straight into slab Kf) --------
    bf16x8 aQ[2][2];
    for (int p = 0; p < 2; p++) {
        const unsigned short* wsrc = p ? wkp : wqp;
        const float* bsrc = p ? bk : bq;
        const float bscl = p ? 1.0f : QSC;
        #pragma unroll
        for (int nt = 0; nt < 4; nt++) {
            bf16x8 aW[2];
            #pragma unroll
            for (int kc = 0; kc < 2; kc++)
                aW[kc] = *(const bf16x8*)(wsrc + (nt * 16 + lc) * 64 + kc * 32 + quad * 8);
            float4 bb = *(const float4*)&bsrc[nt * 16 + quad * 4];
            bb.x *= bscl; bb.y *= bscl; bb.z *= bscl; bb.w *= bscl;
            #pragma unroll
            for (int rt = 0; rt < 2; rt++) {
                f32x4 a = {0.f, 0.f, 0.f, 0.f};
                a = __builtin_amdgcn_mfma_f32_16x16x32_bf16(aW[0], aH[rt][0], a, 0, 0, 0);
                a = __builtin_amdgcn_mfma_f32_16x16x32_bf16(aW[1], aH[rt][1], a, 0, 0, 0);
                us4 pk;
                pk[0] = f2b(a[0] + bb.x); pk[1] = f2b(a[1] + bb.y);
                pk[2] = f2b(a[2] + bb.z); pk[3] = f2b(a[3] + bb.w);
                *(us4*)&Ts[(rt * 16 + lc) * 72 + nt * 16 + quad * 4] = pk;
            }
        }
        #pragma unroll
        for (int rt = 0; rt < 2; rt++)
            #pragma unroll
            for (int kc = 0; kc < 2; kc++) {
                bf16x8 fr = *(const bf16x8*)&Ts[(rt * 16 + lc) * 72 + kc * 32 + quad * 8];
                if (p == 0) aQ[rt][kc] = fr;
                else *(bf16x8*)&Kf[((rt * 2 + kc) << 9) + lane * 8] = fr;
            }
    }

    // ---- P3c: v -> Vf, B-frag lane-linear (frag stride 512 shorts) -------
    #pragma unroll
    for (int nt = 0; nt < 4; nt++) {
        bf16x8 bW[2];
        #pragma unroll
        for (int kc = 0; kc < 2; kc++)
            bW[kc] = *(const bf16x8*)(wvp + (nt * 16 + lc) * 64 + kc * 32 + quad * 8);
        const float bvv = bvp[nt * 16 + lc];
        #pragma unroll
        for (int rt = 0; rt < 2; rt++) {
            f32x4 a = {0.f, 0.f, 0.f, 0.f};
            a = __builtin_amdgcn_mfma_f32_16x16x32_bf16(aH[rt][0], bW[0], a, 0, 0, 0);
            a = __builtin_amdgcn_mfma_f32_16x16x32_bf16(aH[rt][1], bW[1], a, 0, 0, 0);
            us4 pk;
            pk[0] = f2b(a[0] + bvv); pk[1] = f2b(a[1] + bvv);
            pk[2] = f2b(a[2] + bvv); pk[3] = f2b(a[3] + bvv);
            *(us4*)&Vf[nt * 512 + ((rt * 2 + (quad >> 1)) * 16 + lc) * 8 + (quad & 1) * 4] = pk;
        }
    }

    __syncthreads();          // all waves' Kf/Vf ready — only pre-attn barrier

    // ---- attention: single pass, 16 chunks, K-frag register prefetch -----
    f32x4 outacc[2][4];
    #pragma unroll
    for (int rt = 0; rt < 2; rt++)
        #pragma unroll
        for (int dt = 0; dt < 4; dt++) outacc[rt][dt] = (f32x4){0.f, 0.f, 0.f, 0.f};
    float den[2][4] = {{0.f, 0.f, 0.f, 0.f}, {0.f, 0.f, 0.f, 0.f}};

    bf16x8 bK[2][2], bKn[2][2];
    {
        const unsigned short* sK = (const unsigned short*)smem;   // chunk 0
        #pragma unroll
        for (int nt = 0; nt < 2; nt++)
            #pragma unroll
            for (int kc = 0; kc < 2; kc++)
                bK[nt][kc] = *(const bf16x8*)&sK[((nt * 2 + kc) << 9) + lane * 8];
    }

    for (int cc = 0; cc < 16; cc++) {
        f32x4 sv[2][2];
        #pragma unroll
        for (int rt = 0; rt < 2; rt++)
            #pragma unroll
            for (int nt = 0; nt < 2; nt++) {
                f32x4 z = {0.f, 0.f, 0.f, 0.f};
                z = __builtin_amdgcn_mfma_f32_16x16x32_bf16(aQ[rt][0], bK[nt][0], z, 0, 0, 0);
                sv[rt][nt] = __builtin_amdgcn_mfma_f32_16x16x32_bf16(aQ[rt][1], bK[nt][1], z, 0, 0, 0);
            }
        const unsigned short* sV = (const unsigned short*)(smem + cc * SLAB + 4096);
        bf16x8 bV[4];
        #pragma unroll
        for (int dt = 0; dt < 4; dt++)
            bV[dt] = *(const bf16x8*)&sV[dt * 512 + lane * 8];
        #pragma unroll
        for (int nt = 0; nt < 2; nt++)
            #pragma unroll
            for (int reg = 0; reg < 4; reg++) {
                float pr = __builtin_amdgcn_exp2f(sv[0][nt][reg]);  // 1x v_exp_f32
                den[0][reg] += pr;
                Ps[(quad * 4 + reg) * 40 + nt * 16 + lc] = f2b(pr);
            }
        if (cc < 15) {                                // prefetch next K frags
            const unsigned short* sKn = (const unsigned short*)(smem + (cc + 1) * SLAB);
            #pragma unroll
            for (int nt = 0; nt < 2; nt++)
                #pragma unroll
                for (int kc = 0; kc < 2; kc++)
                    bKn[nt][kc] = *(const bf16x8*)&sKn[((nt * 2 + kc) << 9) + lane * 8];
        }
        bf16x8 aP0 = *(const bf16x8*)&Ps[lc * 40 + quad * 8];
        #pragma unroll
        for (int nt = 0; nt < 2; nt++)
            #pragma unroll
            for (int reg = 0; reg < 4; reg++) {
                float pr = __builtin_amdgcn_exp2f(sv[1][nt][reg]);
                den[1][reg] += pr;
                Ps[(quad * 4 + reg) * 40 + nt * 16 + lc] = f2b(pr);
            }
        #pragma unroll
        for (int dt = 0; dt < 4; dt++)
            outacc[0][dt] = __builtin_amdgcn_mfma_f32_16x16x32_bf16(aP0, bV[dt], outacc[0][dt], 0, 0, 0);
        bf16x8 aP1 = *(const bf16x8*)&Ps[lc * 40 + quad * 8];
        #pragma unroll
        for (int dt = 0; dt < 4; dt++)
            outacc[1][dt] = __builtin_amdgcn_mfma_f32_16x16x32_bf16(aP1, bV[dt], outacc[1][dt], 0, 0, 0);
        #pragma unroll
        for (int nt = 0; nt < 2; nt++)
            #pragma unroll
            for (int kc = 0; kc < 2; kc++)
                bK[nt][kc] = bKn[nt][kc];
    }

    // ---- epilogue: den reduce (quad 16-lane classes), pooled, fc ---------
    float rden[2][4];
    #pragma unroll
    for (int rt = 0; rt < 2; rt++)
        #pragma unroll
        for (int reg = 0; reg < 4; reg++) {
            float d2 = den[rt][reg];
            d2 += __shfl_xor(d2, 1);  d2 += __shfl_xor(d2, 2);
            d2 += __shfl_xor(d2, 4);  d2 += __shfl_xor(d2, 8);
            rden[rt][reg] = 1.0f / d2;
        }
    #pragma unroll
    for (int dt = 0; dt < 4; dt++) {
        float ps = 0.f;
        #pragma unroll
        for (int rt = 0; rt < 2; rt++)
            #pragma unroll
            for (int reg = 0; reg < 4; reg++)
                ps += outacc[rt][dt][reg] * rden[rt][reg];
        ps += __shfl_xor(ps, 16);
        ps += __shfl_xor(ps, 32);
        if (quad == 0) redw[dt * 16 + lc] = ps;     // aliases dead Ps
    }
    __syncthreads();
    if (t < 64) {
        float s = 0.f;
        #pragma unroll
        for (int ww = 0; ww < 16; ww++)
            s += *(const float*)(smem + ww * SLAB + 8192 + t * 4);
        pooled[t] = s * (1.0f / 512.0f);
    }
    __syncthreads();
    if (t < NCLASS) {
        float acc = fcb[t];
        #pragma unroll
        for (int d = 0; d < 64; d++) acc += pooled[d] * fcw[t * 64 + d];
        outp[b * NCLASS + t] = acc;
    }
}

// ---------------------------------------------------------------------------
extern "C" void kernel_launch(void* const* d_in, const int* in_sizes, int n_in,
                              void* d_out, int out_size, void* d_ws, size_t ws_size,
                              hipStream_t stream)
{
    const float* x   = (const float*)d_in[0];
    const float* w1  = (const float*)d_in[1];
    const float* cb1 = (const float*)d_in[2];
    const float* g1  = (const float*)d_in[3];
    const float* be1 = (const float*)d_in[4];
    const float* m1  = (const float*)d_in[5];
    const float* v1  = (const float*)d_in[6];
    const float* w2  = (const float*)d_in[7];
    const float* cb2 = (const float*)d_in[8];
    const float* g2  = (const float*)d_in[9];
    const float* be2 = (const float*)d_in[10];
    const float* m2  = (const float*)d_in[11];
    const float* v2  = (const float*)d_in[12];
    const float* wq  = (const float*)d_in[13];
    const float* bq  = (const float*)d_in[14];
    const float* wk  = (const float*)d_in[15];
    const float* bk  = (const float*)d_in[16];
    const float* wv  = (const float*)d_in[17];
    const float* bv  = (const float*)d_in[18];
    const float* fcw = (const float*)d_in[19];
    const float* fcb = (const float*)d_in[20];
    float* out = (float*)d_out;

    char* ws = (char*)d_ws;
    unsigned short* w1p = (unsigned short*)(ws);            // 2048 B
    float*          b1f = (float*)(ws + 2048u);             // 128 B
    float*          b2f = (float*)(ws + 2176u);             // 256 B
    unsigned short* w2p = (unsigned short*)(ws + 2432u);    // 12288 B
    unsigned short* wqp = (unsigned short*)(ws + 14720u);   // 8192 B
    unsigned short* wkp = (unsigned short*)(ws + 22912u);   // 8192 B
    unsigned short* wvp = (unsigned short*)(ws + 31104u);   // 8192 B
    unsigned short* ximg = (unsigned short*)(ws + 40960u);  // 12,582,912 B

    prep_all<<<dim3(NB), 256, 0, stream>>>(x,
                                           w1, cb1, g1, be1, m1, v1,
                                           w2, cb2, g2, be2, m2, v2,
                                           wq, wk, wv,
                                           ximg, w1p, b1f, w2p, b2f, wqp, wkp, wvp);
    fused_all<<<dim3(NB), 1024, 0, stream>>>(ximg, w1p, b1f, w2p, b2f,
                                             wqp, wkp, wvp,
                                             bq, bk, bv, fcw, fcb, out);
}

// Round 17
// 133.636 us; speedup vs baseline: 1.1737x; 1.1233x over previous
//
#include <hip/hip_runtime.h>
#include <hip/hip_bf16.h>

// B=256, C_IN=6, L=512, C1=32, C2=D=64, NCLASS=10.
// Megakernel v8: no im2col tensor. conv1 uses k'=dl*8+ci weight packing so
// A-frag elem u has ci=u (compile-time), dl=quad (lane-uniform): frags gather
// from a 6 KB bf16 x-stage in LDS (18 ds_read_u16/wave). prep = 1-block
// weight fold only (~2us). Attention: single pass, K-frag register prefetch,
// exp via raw v_exp_f32. LDS 157.7 KB. ws: prepped weights only.

#define NB 256
#define LL 512
#define CIN 6
#define NCLASS 10
#define SLAB 9472
#define QSC 0.18033688f   // 0.125 * log2(e): exp(s/8) == exp2(s*QSC)

typedef __bf16 bf16x8 __attribute__((ext_vector_type(8)));
typedef float f32x4 __attribute__((ext_vector_type(4)));
typedef unsigned short us4 __attribute__((ext_vector_type(4)));

static __device__ __forceinline__ unsigned short f2b(float f) {
    __bf16 h = (__bf16)f;                       // RNE f32->bf16
    return __builtin_bit_cast(unsigned short, h);
}

// ---------------------------------------------------------------------------
// Kernel P: 1-block weight fold (~2 us).
// w1p[c][k'=dl*8+ci] = w1[c][ci*3+dl]*inv1 (zeros at ci>=6 or dl==3).
// w2p[c2][k'=dl*32+ci]*inv2; b1f/b2f folded; wqp = wq*QSC; wkp; wvp.
// ---------------------------------------------------------------------------
__global__ __launch_bounds__(256) void prep_weights(
    const float* __restrict__ w1, const float* __restrict__ cb1,
    const float* __restrict__ g1, const float* __restrict__ be1,
    const float* __restrict__ m1, const float* __restrict__ v1,
    const float* __restrict__ w2, const float* __restrict__ cb2,
    const float* __restrict__ g2, const float* __restrict__ be2,
    const float* __restrict__ m2, const float* __restrict__ v2,
    const float* __restrict__ wq, const float* __restrict__ wk,
    const float* __restrict__ wv,
    unsigned short* __restrict__ w1p, float* __restrict__ b1f,
    unsigned short* __restrict__ w2p, float* __restrict__ b2f,
    unsigned short* __restrict__ wqp, unsigned short* __restrict__ wkp,
    unsigned short* __restrict__ wvp)
{
    const int t = threadIdx.x;
    for (int idx = t; idx < 1024; idx += 256) {       // w1p [32][32], k'=dl*8+ci
        int c = idx >> 5, k = idx & 31;
        int dl = k >> 3, ci = k & 7;
        float inv = g1[c] * rsqrtf(v1[c] + 1e-5f);
        float val = (dl < 3 && ci < 6) ? w1[c * 18 + ci * 3 + dl] * inv : 0.f;
        w1p[idx] = f2b(val);
    }
    if (t < 32) {
        float inv = g1[t] * rsqrtf(v1[t] + 1e-5f);
        b1f[t] = be1[t] + (cb1[t] - m1[t]) * inv;
    }
    for (int idx = t; idx < 2048; idx += 256) {       // w2p [64][96], k'=dl*32+ci
        int c2 = idx >> 5, ci = idx & 31;
        float inv = g2[c2] * rsqrtf(v2[c2] + 1e-5f);
        const float* wp = w2 + c2 * 96 + ci * 3;
        w2p[c2 * 96 +      ci] = f2b(wp[0] * inv);
        w2p[c2 * 96 + 32 + ci] = f2b(wp[1] * inv);
        w2p[c2 * 96 + 64 + ci] = f2b(wp[2] * inv);
    }
    if (t >= 64 && t < 128) {
        int c2 = t - 64;
        float inv = g2[c2] * rsqrtf(v2[c2] + 1e-5f);
        b2f[c2] = be2[c2] + (cb2[c2] - m2[c2]) * inv;
    }
    for (int idx = t; idx < 4096; idx += 256) {
        wqp[idx] = f2b(wq[idx] * QSC);                // fold 1/8 * log2e
        wkp[idx] = f2b(wk[idx]);
        wvp[idx] = f2b(wv[idx]);
    }
}

// ---------------------------------------------------------------------------
// Megakernel v8. Slabs (9472 B/wave) + xstage (6144 B) = 157696 B LDS.
// Slab phases: conv: h1sl[34][40] @3072 | Ts[32][72] @4608
//              attn: Kf @0 (4096) | Vf @4096 (4096) | Ps[16][40] @8192
//              epi : redw f32[64] @8192 (aliases Ps); pooled @ smem+8448
// ---------------------------------------------------------------------------
__global__ __launch_bounds__(1024, 4) void fused_all(
    const float* __restrict__ x,
    const unsigned short* __restrict__ w1p, const float* __restrict__ b1f,
    const unsigned short* __restrict__ w2p, const float* __restrict__ b2f,
    const unsigned short* __restrict__ wqp, const unsigned short* __restrict__ wkp,
    const unsigned short* __restrict__ wvp,
    const float* __restrict__ bq, const float* __restrict__ bk,
    const float* __restrict__ bvp,
    const float* __restrict__ fcw, const float* __restrict__ fcb,
    float* __restrict__ outp)
{
    const int b = blockIdx.x;
    const int t = threadIdx.x;
    const int w = t >> 6, lane = t & 63, quad = lane >> 4, lc = lane & 15;

    __shared__ __align__(16) char smem[16 * SLAB + 6144];   // 157696 B
    char* myslab = smem + w * SLAB;
    unsigned short* h1sl = (unsigned short*)(myslab + 3072);
    unsigned short* Ts   = (unsigned short*)(myslab + 4608);
    unsigned short* Kf   = (unsigned short*)myslab;
    unsigned short* Vf   = (unsigned short*)(myslab + 4096);
    unsigned short* Ps   = (unsigned short*)(myslab + 8192);
    float* redw   = (float*)(myslab + 8192);         // epilogue alias of Ps
    float* pooled = (float*)(smem + 8448);           // slab0, after wave0 redw
    unsigned short* xstage = (unsigned short*)(smem + 16 * SLAB);  // [6][512]

    // ---- P0: stage x[b] as bf16 into block LDS (coalesced) ---------------
    if (t < 768) {
        int ci = t >> 7, j4 = (t & 127) * 4;
        float4 xv = *(const float4*)(x + ((size_t)b * CIN + ci) * LL + j4);
        us4 pk;
        pk[0] = f2b(xv.x); pk[1] = f2b(xv.y); pk[2] = f2b(xv.z); pk[3] = f2b(xv.w);
        *(us4*)&xstage[ci * 512 + j4] = pk;
    }
    __syncthreads();

    // ---- P1: conv1 as MFMA; A-frags gathered from xstage -----------------
    // k'=dl*8+ci: frag elem u -> ci=u, dl=quad; pos shared across u.
    bf16x8 bW1[2];
    #pragma unroll
    for (int nt = 0; nt < 2; nt++)
        bW1[nt] = *(const bf16x8*)(w1p + (nt * 16 + lc) * 32 + quad * 8);
    float b1v[2] = {b1f[lc], b1f[16 + lc]};
    f32x4 h1acc[3][2];
    #pragma unroll
    for (int mt = 0; mt < 3; mt++) {
        int pos = w * 32 - 2 + mt * 16 + lc + quad;
        bool ok = (quad < 3) && (pos >= 0) && (pos < LL);
        int posc = pos < 0 ? 0 : (pos > 511 ? 511 : pos);
        bf16x8 aX;
        #pragma unroll
        for (int u = 0; u < 6; u++) {
            __bf16 vb = __builtin_bit_cast(__bf16, xstage[u * 512 + posc]);
            aX[u] = ok ? vb : (__bf16)0.f;
        }
        aX[6] = (__bf16)0.f; aX[7] = (__bf16)0.f;
        #pragma unroll
        for (int nt = 0; nt < 2; nt++) {
            f32x4 z = {0.f, 0.f, 0.f, 0.f};
            h1acc[mt][nt] = __builtin_amdgcn_mfma_f32_16x16x32_bf16(aX, bW1[nt], z, 0, 0, 0);
        }
    }
    #pragma unroll
    for (int mt = 0; mt < 3; mt++)
        #pragma unroll
        for (int nt = 0; nt < 2; nt++)
            #pragma unroll
            for (int r = 0; r < 4; r++) {
                int j = mt * 16 + quad * 4 + r;
                if (j < 34) {
                    int pos = w * 32 - 1 + j;
                    float y = h1acc[mt][nt][r] + b1v[nt];
                    y = (pos >= 0 && pos < LL && y > 0.f) ? y : 0.f;
                    h1sl[j * 40 + nt * 16 + lc] = f2b(y);
                }
            }

    // ---- P2: conv2 as GEMM (M=64 c2, N=32 rows, K=96; k'=dl*32+ci) -------
    bf16x8 bX[2][3], aW2[4][3];
    #pragma unroll
    for (int rt = 0; rt < 2; rt++)
        #pragma unroll
        for (int kc = 0; kc < 3; kc++)
            bX[rt][kc] = *(const bf16x8*)&h1sl[(rt * 16 + lc + kc) * 40 + quad * 8];
    #pragma unroll
    for (int nt = 0; nt < 4; nt++)
        #pragma unroll
        for (int kc = 0; kc < 3; kc++)
            aW2[nt][kc] = *(const bf16x8*)(w2p + (nt * 16 + lc) * 96 + kc * 32 + quad * 8);

    f32x4 acc2[4][2];
    #pragma unroll
    for (int nt = 0; nt < 4; nt++)
        #pragma unroll
        for (int rt = 0; rt < 2; rt++) {
            f32x4 a = {0.f, 0.f, 0.f, 0.f};
            a = __builtin_amdgcn_mfma_f32_16x16x32_bf16(aW2[nt][0], bX[rt][0], a, 0, 0, 0);
            a = __builtin_amdgcn_mfma_f32_16x16x32_bf16(aW2[nt][1], bX[rt][1], a, 0, 0, 0);
            acc2[nt][rt] = __builtin_amdgcn_mfma_f32_16x16x32_bf16(aW2[nt][2], bX[rt][2], a, 0, 0, 0);
        }

    // ---- P3a: +b2f, relu -> Ts[row][c2] ----------------------------------
    #pragma unroll
    for (int nt = 0; nt < 4; nt++) {
        const float4 bb2 = *(const float4*)&b2f[nt * 16 + quad * 4];
        #pragma unroll
        for (int rt = 0; rt < 2; rt++) {
            us4 pk;
            float y0 = acc2[nt][rt][0] + bb2.x; pk[0] = f2b(y0 > 0.f ? y0 : 0.f);
            float y1 = acc2[nt][rt][1] + bb2.y; pk[1] = f2b(y1 > 0.f ? y1 : 0.f);
            float y2 = acc2[nt][rt][2] + bb2.z; pk[2] = f2b(y2 > 0.f ? y2 : 0.f);
            float y3 = acc2[nt][rt][3] + bb2.w; pk[3] = f2b(y3 > 0.f ? y3 : 0.f);
            *(us4*)&Ts[(rt * 16 + lc) * 72 + nt * 16 + quad * 4] = pk;
        }
    }
    bf16x8 aH[2][2];
    #pragma unroll
    for (int rt = 0; rt < 2; rt++)
        #pragma unroll
        for (int kc = 0; kc < 2; kc++)
            aH[rt][kc] = *(const bf16x8*)&Ts[(rt * 16 + lc) * 72 + kc * 32 + quad * 8];

    // ---- P3b: q (regs, QSC-scaled) then k (straight into slab Kf) --------
    bf16x8 aQ[2][2];
    for (int p = 0; p < 2; p++) {
        const unsigned short* wsrc = p ? wkp : wqp;
        const float* bsrc = p ? bk : bq;
        const float bscl = p ? 1.0f : QSC;
        #pragma unroll
        for (int nt = 0; nt < 4; nt++) {
            bf16x8 aW[2];
            #pragma unroll
            for (int kc = 0; kc < 2; kc++)
                aW[kc] = *(const bf16x8*)(wsrc + (nt * 16 + lc) * 64 + kc * 32 + quad * 8);
            float4 bb = *(const float4*)&bsrc[nt * 16 + quad * 4];
            bb.x *= bscl; bb.y *= bscl; bb.z *= bscl; bb.w *= bscl;
            #pragma unroll
            for (int rt = 0; rt < 2; rt++) {
                f32x4 a = {0.f, 0.f, 0.f, 0.f};
                a = __builtin_amdgcn_mfma_f32_16x16x32_bf16(aW[0], aH[rt][0], a, 0, 0, 0);
                a = __builtin_amdgcn_mfma_f32_16x16x32_bf16(aW[1], aH[rt][1], a, 0, 0, 0);
                us4 pk;
                pk[0] = f2b(a[0] + bb.x); pk[1] = f2b(a[1] + bb.y);
                pk[2] = f2b(a[2] + bb.z); pk[3] = f2b(a[3] + bb.w);
                *(us4*)&Ts[(rt * 16 + lc) * 72 + nt * 16 + quad * 4] = pk;
            }
        }
        #pragma unroll
        for (int rt = 0; rt < 2; rt++)
            #pragma unroll
            for (int kc = 0; kc < 2; kc++) {
                bf16x8 fr = *(const bf16x8*)&Ts[(rt * 16 + lc) * 72 + kc * 32 + quad * 8];
                if (p == 0) aQ[rt][kc] = fr;
                else *(bf16x8*)&Kf[((rt * 2 + kc) << 9) + lane * 8] = fr;
            }
    }

    // ---- P3c: v -> Vf, B-frag lane-linear (frag stride 512 shorts) -------
    #pragma unroll
    for (int nt = 0; nt < 4; nt++) {
        bf16x8 bW[2];
        #pragma unroll
        for (int kc = 0; kc < 2; kc++)
            bW[kc] = *(const bf16x8*)(wvp + (nt * 16 + lc) * 64 + kc * 32 + quad * 8);
        const float bvv = bvp[nt * 16 + lc];
        #pragma unroll
        for (int rt = 0; rt < 2; rt++) {
            f32x4 a = {0.f, 0.f, 0.f, 0.f};
            a = __builtin_amdgcn_mfma_f32_16x16x32_bf16(aH[rt][0], bW[0], a, 0, 0, 0);
            a = __builtin_amdgcn_mfma_f32_16x16x32_bf16(aH[rt][1], bW[1], a, 0, 0, 0);
            us4 pk;
            pk[0] = f2b(a[0] + bvv); pk[1] = f2b(a[1] + bvv);
            pk[2] = f2b(a[2] + bvv); pk[3] = f2b(a[3] + bvv);
            *(us4*)&Vf[nt * 512 + ((rt * 2 + (quad >> 1)) * 16 + lc) * 8 + (quad & 1) * 4] = pk;
        }
    }

    __syncthreads();          // all waves' Kf/Vf ready — only pre-attn barrier

    // ---- attention: single pass, 16 chunks, K-frag register prefetch -----
    f32x4 outacc[2][4];
    #pragma unroll
    for (int rt = 0; rt < 2; rt++)
        #pragma unroll
        for (int dt = 0; dt < 4; dt++) outacc[rt][dt] = (f32x4){0.f, 0.f, 0.f, 0.f};
    float den[2][4] = {{0.f, 0.f, 0.f, 0.f}, {0.f, 0.f, 0.f, 0.f}};

    bf16x8 bK[2][2], bKn[2][2];
    {
        const unsigned short* sK = (const unsigned short*)smem;   // chunk 0
        #pragma unroll
        for (int nt = 0; nt < 2; nt++)
            #pragma unroll
            for (int kc = 0; kc < 2; kc++)
                bK[nt][kc] = *(const bf16x8*)&sK[((nt * 2 + kc) << 9) + lane * 8];
    }

    for (int cc = 0; cc < 16; cc++) {
        f32x4 sv[2][2];
        #pragma unroll
        for (int rt = 0; rt < 2; rt++)
            #pragma unroll
            for (int nt = 0; nt < 2; nt++) {
                f32x4 z = {0.f, 0.f, 0.f, 0.f};
                z = __builtin_amdgcn_mfma_f32_16x16x32_bf16(aQ[rt][0], bK[nt][0], z, 0, 0, 0);
                sv[rt][nt] = __builtin_amdgcn_mfma_f32_16x16x32_bf16(aQ[rt][1], bK[nt][1], z, 0, 0, 0);
            }
        const unsigned short* sV = (const unsigned short*)(smem + cc * SLAB + 4096);
        bf16x8 bV[4];
        #pragma unroll
        for (int dt = 0; dt < 4; dt++)
            bV[dt] = *(const bf16x8*)&sV[dt * 512 + lane * 8];
        #pragma unroll
        for (int nt = 0; nt < 2; nt++)
            #pragma unroll
            for (int reg = 0; reg < 4; reg++) {
                float pr = __builtin_amdgcn_exp2f(sv[0][nt][reg]);  // 1x v_exp_f32
                den[0][reg] += pr;
                Ps[(quad * 4 + reg) * 40 + nt * 16 + lc] = f2b(pr);
            }
        if (cc < 15) {                                // prefetch next K frags
            const unsigned short* sKn = (const unsigned short*)(smem + (cc + 1) * SLAB);
            #pragma unroll
            for (int nt = 0; nt < 2; nt++)
                #pragma unroll
                for (int kc = 0; kc < 2; kc++)
                    bKn[nt][kc] = *(const bf16x8*)&sKn[((nt * 2 + kc) << 9) + lane * 8];
        }
        bf16x8 aP0 = *(const bf16x8*)&Ps[lc * 40 + quad * 8];
        #pragma unroll
        for (int nt = 0; nt < 2; nt++)
            #pragma unroll
            for (int reg = 0; reg < 4; reg++) {
                float pr = __builtin_amdgcn_exp2f(sv[1][nt][reg]);
                den[1][reg] += pr;
                Ps[(quad * 4 + reg) * 40 + nt * 16 + lc] = f2b(pr);
            }
        #pragma unroll
        for (int dt = 0; dt < 4; dt++)
            outacc[0][dt] = __builtin_amdgcn_mfma_f32_16x16x32_bf16(aP0, bV[dt], outacc[0][dt], 0, 0, 0);
        bf16x8 aP1 = *(const bf16x8*)&Ps[lc * 40 + quad * 8];
        #pragma unroll
        for (int dt = 0; dt < 4; dt++)
            outacc[1][dt] = __builtin_amdgcn_mfma_f32_16x16x32_bf16(aP1, bV[dt], outacc[1][dt], 0, 0, 0);
        #pragma unroll
        for (int nt = 0; nt < 2; nt++)
            #pragma unroll
            for (int kc = 0; kc < 2; kc++)
                bK[nt][kc] = bKn[nt][kc];
    }

    // ---- epilogue: den reduce (quad 16-lane classes), pooled, fc ---------
    float rden[2][4];
    #pragma unroll
    for (int rt = 0; rt < 2; rt++)
        #pragma unroll
        for (int reg = 0; reg < 4; reg++) {
            float d2 = den[rt][reg];
            d2 += __shfl_xor(d2, 1);  d2 += __shfl_xor(d2, 2);
            d2 += __shfl_xor(d2, 4);  d2 += __shfl_xor(d2, 8);
            rden[rt][reg] = 1.0f / d2;
        }
    #pragma unroll
    for (int dt = 0; dt < 4; dt++) {
        float ps = 0.f;
        #pragma unroll
        for (int rt = 0; rt < 2; rt++)
            #pragma unroll
            for (int reg = 0; reg < 4; reg++)
                ps += outacc[rt][dt][reg] * rden[rt][reg];
        ps += __shfl_xor(ps, 16);
        ps += __shfl_xor(ps, 32);
        if (quad == 0) redw[dt * 16 + lc] = ps;     // aliases dead Ps
    }
    __syncthreads();
    if (t < 64) {
        float s = 0.f;
        #pragma unroll
        for (int ww = 0; ww < 16; ww++)
            s += *(const float*)(smem + ww * SLAB + 8192 + t * 4);
        pooled[t] = s * (1.0f / 512.0f);
    }
    __syncthreads();
    if (t < NCLASS) {
        float acc = fcb[t];
        #pragma unroll
        for (int d = 0; d < 64; d++) acc += pooled[d] * fcw[t * 64 + d];
        outp[b * NCLASS + t] = acc;
    }
}

// ---------------------------------------------------------------------------
extern "C" void kernel_launch(void* const* d_in, const int* in_sizes, int n_in,
                              void* d_out, int out_size, void* d_ws, size_t ws_size,
                              hipStream_t stream)
{
    const float* x   = (const float*)d_in[0];
    const float* w1  = (const float*)d_in[1];
    const float* cb1 = (const float*)d_in[2];
    const float* g1  = (const float*)d_in[3];
    const float* be1 = (const float*)d_in[4];
    const float* m1  = (const float*)d_in[5];
    const float* v1  = (const float*)d_in[6];
    const float* w2  = (const float*)d_in[7];
    const float* cb2 = (const float*)d_in[8];
    const float* g2  = (const float*)d_in[9];
    const float* be2 = (const float*)d_in[10];
    const float* m2  = (const float*)d_in[11];
    const float* v2  = (const float*)d_in[12];
    const float* wq  = (const float*)d_in[13];
    const float* bq  = (const float*)d_in[14];
    const float* wk  = (const float*)d_in[15];
    const float* bk  = (const float*)d_in[16];
    const float* wv  = (const float*)d_in[17];
    const float* bv  = (const float*)d_in[18];
    const float* fcw = (const float*)d_in[19];
    const float* fcb = (const float*)d_in[20];
    float* out = (float*)d_out;

    char* ws = (char*)d_ws;
    unsigned short* w1p = (unsigned short*)(ws);            // 2048 B
    float*          b1f = (float*)(ws + 2048u);             // 128 B
    float*          b2f = (float*)(ws + 2176u);             // 256 B
    unsigned short* w2p = (unsigned short*)(ws + 2432u);    // 12288 B
    unsigned short* wqp = (unsigned short*)(ws + 14720u);   // 8192 B
    unsigned short* wkp = (unsigned short*)(ws + 22912u);   // 8192 B
    unsigned short* wvp = (unsigned short*)(ws + 31104u);   // 8192 B

    prep_weights<<<dim3(1), 256, 0, stream>>>(w1, cb1, g1, be1, m1, v1,
                                              w2, cb2, g2, be2, m2, v2,
                                              wq, wk, wv,
                                              w1p, b1f, w2p, b2f, wqp, wkp, wvp);
    fused_all<<<dim3(NB), 1024, 0, stream>>>(x, w1p, b1f, w2p, b2f,
                                             wqp, wkp, wvp,
                                             bq, bk, bv, fcw, fcb, out);
}

// Round 18
// 133.057 us; speedup vs baseline: 1.1788x; 1.0044x over previous
//
#include <hip/hip_runtime.h>
#include <hip/hip_bf16.h>

// B=256, C_IN=6, L=512, C1=32, C2=D=64, NCLASS=10.
// Megakernel v9: v8 + k-permutation in attention (k' = (key&15)*2 + key>>4,
// applied identically to P and V so the MFMA k-reduction is unchanged).
// This packs the per-chunk Ps C->A transform writes as b32 pairs: 8 writes
// instead of 16 scalar (-128 DS ops/wave over 16 chunks; the CU-shared DS
// pipe is the measured bottleneck). One-time cost: P3c V store becomes 32
// scalar u16 writes. LDS 157.7 KB. ws: prepped weights only.

#define NB 256
#define LL 512
#define CIN 6
#define NCLASS 10
#define SLAB 9472
#define QSC 0.18033688f   // 0.125 * log2(e): exp(s/8) == exp2(s*QSC)

typedef __bf16 bf16x8 __attribute__((ext_vector_type(8)));
typedef float f32x4 __attribute__((ext_vector_type(4)));
typedef unsigned short us4 __attribute__((ext_vector_type(4)));

static __device__ __forceinline__ unsigned short f2b(float f) {
    __bf16 h = (__bf16)f;                       // RNE f32->bf16
    return __builtin_bit_cast(unsigned short, h);
}

// ---------------------------------------------------------------------------
// Kernel P: 1-block weight fold (~2 us).
// w1p[c][k'=dl*8+ci] = w1[c][ci*3+dl]*inv1 (zeros at ci>=6 or dl==3).
// w2p[c2][k'=dl*32+ci]*inv2; b1f/b2f folded; wqp = wq*QSC; wkp; wvp.
// ---------------------------------------------------------------------------
__global__ __launch_bounds__(256) void prep_weights(
    const float* __restrict__ w1, const float* __restrict__ cb1,
    const float* __restrict__ g1, const float* __restrict__ be1,
    const float* __restrict__ m1, const float* __restrict__ v1,
    const float* __restrict__ w2, const float* __restrict__ cb2,
    const float* __restrict__ g2, const float* __restrict__ be2,
    const float* __restrict__ m2, const float* __restrict__ v2,
    const float* __restrict__ wq, const float* __restrict__ wk,
    const float* __restrict__ wv,
    unsigned short* __restrict__ w1p, float* __restrict__ b1f,
    unsigned short* __restrict__ w2p, float* __restrict__ b2f,
    unsigned short* __restrict__ wqp, unsigned short* __restrict__ wkp,
    unsigned short* __restrict__ wvp)
{
    const int t = threadIdx.x;
    for (int idx = t; idx < 1024; idx += 256) {       // w1p [32][32], k'=dl*8+ci
        int c = idx >> 5, k = idx & 31;
        int dl = k >> 3, ci = k & 7;
        float inv = g1[c] * rsqrtf(v1[c] + 1e-5f);
        float val = (dl < 3 && ci < 6) ? w1[c * 18 + ci * 3 + dl] * inv : 0.f;
        w1p[idx] = f2b(val);
    }
    if (t < 32) {
        float inv = g1[t] * rsqrtf(v1[t] + 1e-5f);
        b1f[t] = be1[t] + (cb1[t] - m1[t]) * inv;
    }
    for (int idx = t; idx < 2048; idx += 256) {       // w2p [64][96], k'=dl*32+ci
        int c2 = idx >> 5, ci = idx & 31;
        float inv = g2[c2] * rsqrtf(v2[c2] + 1e-5f);
        const float* wp = w2 + c2 * 96 + ci * 3;
        w2p[c2 * 96 +      ci] = f2b(wp[0] * inv);
        w2p[c2 * 96 + 32 + ci] = f2b(wp[1] * inv);
        w2p[c2 * 96 + 64 + ci] = f2b(wp[2] * inv);
    }
    if (t >= 64 && t < 128) {
        int c2 = t - 64;
        float inv = g2[c2] * rsqrtf(v2[c2] + 1e-5f);
        b2f[c2] = be2[c2] + (cb2[c2] - m2[c2]) * inv;
    }
    for (int idx = t; idx < 4096; idx += 256) {
        wqp[idx] = f2b(wq[idx] * QSC);                // fold 1/8 * log2e
        wkp[idx] = f2b(wk[idx]);
        wvp[idx] = f2b(wv[idx]);
    }
}

// ---------------------------------------------------------------------------
// Megakernel v9. Slabs (9472 B/wave) + xstage (6144 B) = 157696 B LDS.
// Slab phases: conv: h1sl[34][40] @3072 | Ts[32][72] @4608
//              attn: Kf @0 (4096) | Vf @4096 (4096, k'-permuted) | Ps @8192
//              epi : redw f32[64] @8192 (aliases Ps); pooled @ smem+8448
// ---------------------------------------------------------------------------
__global__ __launch_bounds__(1024, 4) void fused_all(
    const float* __restrict__ x,
    const unsigned short* __restrict__ w1p, const float* __restrict__ b1f,
    const unsigned short* __restrict__ w2p, const float* __restrict__ b2f,
    const unsigned short* __restrict__ wqp, const unsigned short* __restrict__ wkp,
    const unsigned short* __restrict__ wvp,
    const float* __restrict__ bq, const float* __restrict__ bk,
    const float* __restrict__ bvp,
    const float* __restrict__ fcw, const float* __restrict__ fcb,
    float* __restrict__ outp)
{
    const int b = blockIdx.x;
    const int t = threadIdx.x;
    const int w = t >> 6, lane = t & 63, quad = lane >> 4, lc = lane & 15;

    __shared__ __align__(16) char smem[16 * SLAB + 6144];   // 157696 B
    char* myslab = smem + w * SLAB;
    unsigned short* h1sl = (unsigned short*)(myslab + 3072);
    unsigned short* Ts   = (unsigned short*)(myslab + 4608);
    unsigned short* Kf   = (unsigned short*)myslab;
    unsigned short* Vf   = (unsigned short*)(myslab + 4096);
    unsigned short* Ps   = (unsigned short*)(myslab + 8192);
    float* redw   = (float*)(myslab + 8192);         // epilogue alias of Ps
    float* pooled = (float*)(smem + 8448);           // slab0, after wave0 redw
    unsigned short* xstage = (unsigned short*)(smem + 16 * SLAB);  // [6][512]

    // ---- P0: stage x[b] as bf16 into block LDS (coalesced) ---------------
    if (t < 768) {
        int ci = t >> 7, j4 = (t & 127) * 4;
        float4 xv = *(const float4*)(x + ((size_t)b * CIN + ci) * LL + j4);
        us4 pk;
        pk[0] = f2b(xv.x); pk[1] = f2b(xv.y); pk[2] = f2b(xv.z); pk[3] = f2b(xv.w);
        *(us4*)&xstage[ci * 512 + j4] = pk;
    }
    __syncthreads();

    // ---- P1: conv1 as MFMA; A-frags gathered from xstage -----------------
    // k'=dl*8+ci: frag elem u -> ci=u, dl=quad; pos shared across u.
    bf16x8 bW1[2];
    #pragma unroll
    for (int nt = 0; nt < 2; nt++)
        bW1[nt] = *(const bf16x8*)(w1p + (nt * 16 + lc) * 32 + quad * 8);
    float b1v[2] = {b1f[lc], b1f[16 + lc]};
    f32x4 h1acc[3][2];
    #pragma unroll
    for (int mt = 0; mt < 3; mt++) {
        int pos = w * 32 - 2 + mt * 16 + lc + quad;
        bool ok = (quad < 3) && (pos >= 0) && (pos < LL);
        int posc = pos < 0 ? 0 : (pos > 511 ? 511 : pos);
        bf16x8 aX;
        #pragma unroll
        for (int u = 0; u < 6; u++) {
            __bf16 vb = __builtin_bit_cast(__bf16, xstage[u * 512 + posc]);
            aX[u] = ok ? vb : (__bf16)0.f;
        }
        aX[6] = (__bf16)0.f; aX[7] = (__bf16)0.f;
        #pragma unroll
        for (int nt = 0; nt < 2; nt++) {
            f32x4 z = {0.f, 0.f, 0.f, 0.f};
            h1acc[mt][nt] = __builtin_amdgcn_mfma_f32_16x16x32_bf16(aX, bW1[nt], z, 0, 0, 0);
        }
    }
    #pragma unroll
    for (int mt = 0; mt < 3; mt++)
        #pragma unroll
        for (int nt = 0; nt < 2; nt++)
            #pragma unroll
            for (int r = 0; r < 4; r++) {
                int j = mt * 16 + quad * 4 + r;
                if (j < 34) {
                    int pos = w * 32 - 1 + j;
                    float y = h1acc[mt][nt][r] + b1v[nt];
                    y = (pos >= 0 && pos < LL && y > 0.f) ? y : 0.f;
                    h1sl[j * 40 + nt * 16 + lc] = f2b(y);
                }
            }

    // ---- P2: conv2 as GEMM (M=64 c2, N=32 rows, K=96; k'=dl*32+ci) -------
    bf16x8 bX[2][3], aW2[4][3];
    #pragma unroll
    for (int rt = 0; rt < 2; rt++)
        #pragma unroll
        for (int kc = 0; kc < 3; kc++)
            bX[rt][kc] = *(const bf16x8*)&h1sl[(rt * 16 + lc + kc) * 40 + quad * 8];
    #pragma unroll
    for (int nt = 0; nt < 4; nt++)
        #pragma unroll
        for (int kc = 0; kc < 3; kc++)
            aW2[nt][kc] = *(const bf16x8*)(w2p + (nt * 16 + lc) * 96 + kc * 32 + quad * 8);

    f32x4 acc2[4][2];
    #pragma unroll
    for (int nt = 0; nt < 4; nt++)
        #pragma unroll
        for (int rt = 0; rt < 2; rt++) {
            f32x4 a = {0.f, 0.f, 0.f, 0.f};
            a = __builtin_amdgcn_mfma_f32_16x16x32_bf16(aW2[nt][0], bX[rt][0], a, 0, 0, 0);
            a = __builtin_amdgcn_mfma_f32_16x16x32_bf16(aW2[nt][1], bX[rt][1], a, 0, 0, 0);
            acc2[nt][rt] = __builtin_amdgcn_mfma_f32_16x16x32_bf16(aW2[nt][2], bX[rt][2], a, 0, 0, 0);
        }

    // ---- P3a: +b2f, relu -> Ts[row][c2] ----------------------------------
    #pragma unroll
    for (int nt = 0; nt < 4; nt++) {
        const float4 bb2 = *(const float4*)&b2f[nt * 16 + quad * 4];
        #pragma unroll
        for (int rt = 0; rt < 2; rt++) {
            us4 pk;
            float y0 = acc2[nt][rt][0] + bb2.x; pk[0] = f2b(y0 > 0.f ? y0 : 0.f);
            float y1 = acc2[nt][rt][1] + bb2.y; pk[1] = f2b(y1 > 0.f ? y1 : 0.f);
            float y2 = acc2[nt][rt][2] + bb2.z; pk[2] = f2b(y2 > 0.f ? y2 : 0.f);
            float y3 = acc2[nt][rt][3] + bb2.w; pk[3] = f2b(y3 > 0.f ? y3 : 0.f);
            *(us4*)&Ts[(rt * 16 + lc) * 72 + nt * 16 + quad * 4] = pk;
        }
    }
    bf16x8 aH[2][2];
    #pragma unroll
    for (int rt = 0; rt < 2; rt++)
        #pragma unroll
        for (int kc = 0; kc < 2; kc++)
            aH[rt][kc] = *(const bf16x8*)&Ts[(rt * 16 + lc) * 72 + kc * 32 + quad * 8];

    // ---- P3b: q (regs, QSC-scaled) then k (straight into slab Kf) --------
    bf16x8 aQ[2][2];
    for (int p = 0; p < 2; p++) {
        const unsigned short* wsrc = p ? wkp : wqp;
        const float* bsrc = p ? bk : bq;
        const float bscl = p ? 1.0f : QSC;
        #pragma unroll
        for (int nt = 0; nt < 4; nt++) {
            bf16x8 aW[2];
            #pragma unroll
            for (int kc = 0; kc < 2; kc++)
                aW[kc] = *(const bf16x8*)(wsrc + (nt * 16 + lc) * 64 + kc * 32 + quad * 8);
            float4 bb = *(const float4*)&bsrc[nt * 16 + quad * 4];
            bb.x *= bscl; bb.y *= bscl; bb.z *= bscl; bb.w *= bscl;
            #pragma unroll
            for (int rt = 0; rt < 2; rt++) {
                f32x4 a = {0.f, 0.f, 0.f, 0.f};
                a = __builtin_amdgcn_mfma_f32_16x16x32_bf16(aW[0], aH[rt][0], a, 0, 0, 0);
                a = __builtin_amdgcn_mfma_f32_16x16x32_bf16(aW[1], aH[rt][1], a, 0, 0, 0);
                us4 pk;
                pk[0] = f2b(a[0] + bb.x); pk[1] = f2b(a[1] + bb.y);
                pk[2] = f2b(a[2] + bb.z); pk[3] = f2b(a[3] + bb.w);
                *(us4*)&Ts[(rt * 16 + lc) * 72 + nt * 16 + quad * 4] = pk;
            }
        }
        #pragma unroll
        for (int rt = 0; rt < 2; rt++)
            #pragma unroll
            for (int kc = 0; kc < 2; kc++) {
                bf16x8 fr = *(const bf16x8*)&Ts[(rt * 16 + lc) * 72 + kc * 32 + quad * 8];
                if (p == 0) aQ[rt][kc] = fr;
                else *(bf16x8*)&Kf[((rt * 2 + kc) << 9) + lane * 8] = fr;
            }
    }

    // ---- P3c: v -> Vf in k'-PERMUTED B-frag order ------------------------
    // C elem: key = rt*16 + quad*4 + reg, d = nt*16 + lc.
    // k' = (key&15)*2 + (key>>4) = quad*8 + reg*2 + rt  ->  frag nt,
    // position (quad*16 + lc)*8 + reg*2 + rt  (scalar u16 stores).
    #pragma unroll
    for (int nt = 0; nt < 4; nt++) {
        bf16x8 bW[2];
        #pragma unroll
        for (int kc = 0; kc < 2; kc++)
            bW[kc] = *(const bf16x8*)(wvp + (nt * 16 + lc) * 64 + kc * 32 + quad * 8);
        const float bvv = bvp[nt * 16 + lc];
        #pragma unroll
        for (int rt = 0; rt < 2; rt++) {
            f32x4 a = {0.f, 0.f, 0.f, 0.f};
            a = __builtin_amdgcn_mfma_f32_16x16x32_bf16(aH[rt][0], bW[0], a, 0, 0, 0);
            a = __builtin_amdgcn_mfma_f32_16x16x32_bf16(aH[rt][1], bW[1], a, 0, 0, 0);
            #pragma unroll
            for (int reg = 0; reg < 4; reg++)
                Vf[nt * 512 + (quad * 16 + lc) * 8 + reg * 2 + rt] = f2b(a[reg] + bvv);
        }
    }

    __syncthreads();          // all waves' Kf/Vf ready — only pre-attn barrier

    // ---- attention: single pass, 16 chunks, K-frag register prefetch -----
    // P written in k' order as packed b32 pairs; V frags already k'-ordered.
    f32x4 outacc[2][4];
    #pragma unroll
    for (int rt = 0; rt < 2; rt++)
        #pragma unroll
        for (int dt = 0; dt < 4; dt++) outacc[rt][dt] = (f32x4){0.f, 0.f, 0.f, 0.f};
    float den[2][4] = {{0.f, 0.f, 0.f, 0.f}, {0.f, 0.f, 0.f, 0.f}};

    bf16x8 bK[2][2], bKn[2][2];
    {
        const unsigned short* sK = (const unsigned short*)smem;   // chunk 0
        #pragma unroll
        for (int nt = 0; nt < 2; nt++)
            #pragma unroll
            for (int kc = 0; kc < 2; kc++)
                bK[nt][kc] = *(const bf16x8*)&sK[((nt * 2 + kc) << 9) + lane * 8];
    }

    for (int cc = 0; cc < 16; cc++) {
        f32x4 sv[2][2];
        #pragma unroll
        for (int rt = 0; rt < 2; rt++)
            #pragma unroll
            for (int nt = 0; nt < 2; nt++) {
                f32x4 z = {0.f, 0.f, 0.f, 0.f};
                z = __builtin_amdgcn_mfma_f32_16x16x32_bf16(aQ[rt][0], bK[nt][0], z, 0, 0, 0);
                sv[rt][nt] = __builtin_amdgcn_mfma_f32_16x16x32_bf16(aQ[rt][1], bK[nt][1], z, 0, 0, 0);
            }
        const unsigned short* sV = (const unsigned short*)(smem + cc * SLAB + 4096);
        bf16x8 bV[4];
        #pragma unroll
        for (int dt = 0; dt < 4; dt++)
            bV[dt] = *(const bf16x8*)&sV[dt * 512 + lane * 8];
        // exp rt0 -> Ps, packed b32 per reg (k' = lc*2 + nt)
        #pragma unroll
        for (int reg = 0; reg < 4; reg++) {
            float p0 = __builtin_amdgcn_exp2f(sv[0][0][reg]);
            float p1 = __builtin_amdgcn_exp2f(sv[0][1][reg]);
            den[0][reg] += p0 + p1;
            unsigned pk32 = (unsigned)f2b(p0) | ((unsigned)f2b(p1) << 16);
            *(unsigned*)&Ps[(quad * 4 + reg) * 40 + lc * 2] = pk32;
        }
        if (cc < 15) {                                // prefetch next K frags
            const unsigned short* sKn = (const unsigned short*)(smem + (cc + 1) * SLAB);
            #pragma unroll
            for (int nt = 0; nt < 2; nt++)
                #pragma unroll
                for (int kc = 0; kc < 2; kc++)
                    bKn[nt][kc] = *(const bf16x8*)&sKn[((nt * 2 + kc) << 9) + lane * 8];
        }
        bf16x8 aP0 = *(const bf16x8*)&Ps[lc * 40 + quad * 8];
        // exp rt1 -> Ps (fills aP0's DS wait shadow; in-order pipe keeps aP0 safe)
        #pragma unroll
        for (int reg = 0; reg < 4; reg++) {
            float p0 = __builtin_amdgcn_exp2f(sv[1][0][reg]);
            float p1 = __builtin_amdgcn_exp2f(sv[1][1][reg]);
            den[1][reg] += p0 + p1;
            unsigned pk32 = (unsigned)f2b(p0) | ((unsigned)f2b(p1) << 16);
            *(unsigned*)&Ps[(quad * 4 + reg) * 40 + lc * 2] = pk32;
        }
        #pragma unroll
        for (int dt = 0; dt < 4; dt++)
            outacc[0][dt] = __builtin_amdgcn_mfma_f32_16x16x32_bf16(aP0, bV[dt], outacc[0][dt], 0, 0, 0);
        bf16x8 aP1 = *(const bf16x8*)&Ps[lc * 40 + quad * 8];
        #pragma unroll
        for (int dt = 0; dt < 4; dt++)
            outacc[1][dt] = __builtin_amdgcn_mfma_f32_16x16x32_bf16(aP1, bV[dt], outacc[1][dt], 0, 0, 0);
        #pragma unroll
        for (int nt = 0; nt < 2; nt++)
            #pragma unroll
            for (int kc = 0; kc < 2; kc++)
                bK[nt][kc] = bKn[nt][kc];
    }

    // ---- epilogue: den reduce (quad 16-lane classes), pooled, fc ---------
    float rden[2][4];
    #pragma unroll
    for (int rt = 0; rt < 2; rt++)
        #pragma unroll
        for (int reg = 0; reg < 4; reg++) {
            float d2 = den[rt][reg];
            d2 += __shfl_xor(d2, 1);  d2 += __shfl_xor(d2, 2);
            d2 += __shfl_xor(d2, 4);  d2 += __shfl_xor(d2, 8);
            rden[rt][reg] = 1.0f / d2;
        }
    #pragma unroll
    for (int dt = 0; dt < 4; dt++) {
        float ps = 0.f;
        #pragma unroll
        for (int rt = 0; rt < 2; rt++)
            #pragma unroll
            for (int reg = 0; reg < 4; reg++)
                ps += outacc[rt][dt][reg] * rden[rt][reg];
        ps += __shfl_xor(ps, 16);
        ps += __shfl_xor(ps, 32);
        if (quad == 0) redw[dt * 16 + lc] = ps;     // aliases dead Ps
    }
    __syncthreads();
    if (t < 64) {
        float s = 0.f;
        #pragma unroll
        for (int ww = 0; ww < 16; ww++)
            s += *(const float*)(smem + ww * SLAB + 8192 + t * 4);
        pooled[t] = s * (1.0f / 512.0f);
    }
    __syncthreads();
    if (t < NCLASS) {
        float acc = fcb[t];
        #pragma unroll
        for (int d = 0; d < 64; d++) acc += pooled[d] * fcw[t * 64 + d];
        outp[b * NCLASS + t] = acc;
    }
}

// ---------------------------------------------------------------------------
extern "C" void kernel_launch(void* const* d_in, const int* in_sizes, int n_in,
                              void* d_out, int out_size, void* d_ws, size_t ws_size,
                              hipStream_t stream)
{
    const float* x   = (const float*)d_in[0];
    const float* w1  = (const float*)d_in[1];
    const float* cb1 = (const float*)d_in[2];
    const float* g1  = (const float*)d_in[3];
    const float* be1 = (const float*)d_in[4];
    const float* m1  = (const float*)d_in[5];
    const float* v1  = (const float*)d_in[6];
    const float* w2  = (const float*)d_in[7];
    const float* cb2 = (const float*)d_in[8];
    const float* g2  = (const float*)d_in[9];
    const float* be2 = (const float*)d_in[10];
    const float* m2  = (const float*)d_in[11];
    const float* v2  = (const float*)d_in[12];
    const float* wq  = (const float*)d_in[13];
    const float* bq  = (const float*)d_in[14];
    const float* wk  = (const float*)d_in[15];
    const float* bk  = (const float*)d_in[16];
    const float* wv  = (const float*)d_in[17];
    const float* bv  = (const float*)d_in[18];
    const float* fcw = (const float*)d_in[19];
    const float* fcb = (const float*)d_in[20];
    float* out = (float*)d_out;

    char* ws = (char*)d_ws;
    unsigned short* w1p = (unsigned short*)(ws);            // 2048 B
    float*          b1f = (float*)(ws + 2048u);             // 128 B
    float*          b2f = (float*)(ws + 2176u);             // 256 B
    unsigned short* w2p = (unsigned short*)(ws + 2432u);    // 12288 B
    unsigned short* wqp = (unsigned short*)(ws + 14720u);   // 8192 B
    unsigned short* wkp = (unsigned short*)(ws + 22912u);   // 8192 B
    unsigned short* wvp = (unsigned short*)(ws + 31104u);   // 8192 B

    prep_weights<<<dim3(1), 256, 0, stream>>>(w1, cb1, g1, be1, m1, v1,
                                              w2, cb2, g2, be2, m2, v2,
                                              wq, wk, wv,
                                              w1p, b1f, w2p, b2f, wqp, wkp, wvp);
    fused_all<<<dim3(NB), 1024, 0, stream>>>(x, w1p, b1f, w2p, b2f,
                                             wqp, wkp, wvp,
                                             bq, bk, bv, fcw, fcb, out);
}